// Round 3
// baseline (282.219 us; speedup 1.0000x reference)
//
#include <hip/hip_runtime.h>
#include <cstdint>

#define NBATCH 16
#define CCH    384
#define HW     64
#define PLANE  (HW*HW)
#define NTOT   (NBATCH*PLANE)   // 65536 GEMM columns

typedef __attribute__((ext_vector_type(8))) short short8v;
typedef __attribute__((ext_vector_type(4))) float f32x4;
typedef __attribute__((ext_vector_type(2))) float f32x2;

static __device__ __forceinline__ unsigned short f2bf(float f) {
    unsigned int x = __float_as_uint(f);
    unsigned int r = (x + 0x7fffu + ((x >> 16) & 1u)) >> 16;   // RTN-even
    return (unsigned short)r;
}

// ---------------- fused depthwise kernel v2 ----------------
// one block (256 thr) per (n,c) plane; thread = one 1x16 row segment.
// stage 1 (5x5) reads x straight from global (L1-resident plane).
// 'initial' lives in LDS: 84 rows x 384B, XOR-swizzled (cbyte ^ ((row&7)<<4)).
#define IP_ROWB 384
#define IP_R    84
#define IP_R0   10
// col w stored at float offset 12 + w  (12 left halo, 20 right halo floats)

__global__ __launch_bounds__(256, 4)
void dw_fused(const float* __restrict__ x,
              const float* __restrict__ w0, const float* __restrict__ b0,
              const float* __restrict__ w1, const float* __restrict__ b1,
              const float* __restrict__ w2, const float* __restrict__ b2,
              const float* __restrict__ w3, const float* __restrict__ b3,
              const float* __restrict__ w4, const float* __restrict__ b4,
              const float* __restrict__ w5, const float* __restrict__ b5,
              const float* __restrict__ w6, const float* __restrict__ b6,
              unsigned short* __restrict__ spB)
{
    __shared__ char  ipb[IP_R * IP_ROWB];   // 32256 B
    __shared__ float sw0[25];
    __shared__ float swh[21];
    __shared__ float swv[21];
    __shared__ float sb[2];

    const int tid = threadIdx.x;
    const int n   = blockIdx.x / CCH;
    const int c   = blockIdx.x % CCH;

    // ---- per-channel weights (combined 1-D kernels) ----
    if (tid < 25) {
        sw0[tid] = w0[c * 25 + tid];
    } else if (tid < 46) {                    // horizontal: w5(21)+w3(11)+w1(7)
        const int d = tid - 25, dj = d - 10;
        float v = w5[c * 21 + d];
        if (dj >= -5 && dj <= 5) v += w3[c * 11 + dj + 5];
        if (dj >= -3 && dj <= 3) v += w1[c * 7  + dj + 3];
        swh[d] = v;
    } else if (tid < 67) {                    // vertical: w6(21)+w4(11)+w2(7)
        const int d = tid - 46, di = d - 10;
        float v = w6[c * 21 + d];
        if (di >= -5 && di <= 5) v += w4[c * 11 + di + 5];
        if (di >= -3 && di <= 3) v += w2[c * 7  + di + 3];
        swv[d] = v;
    } else if (tid == 67) {
        sb[0] = b0[c];
    } else if (tid == 68) {
        sb[1] = b1[c] + b2[c] + b3[c] + b4[c] + b5[c] + b6[c];
    }

    // ---- zero ip (linear; full zeroing is swizzle-invariant) ----
    {
        const float4 z = make_float4(0.f, 0.f, 0.f, 0.f);
        #pragma unroll
        for (int k = 0; k < 8; ++k) {
            const int i = tid + 256 * k;
            if (i < (IP_R * IP_ROWB) / 16)
                *reinterpret_cast<float4*>(ipb + i * 16) = z;
        }
    }
    __syncthreads();   // weights + zeros visible

    const int h  = tid >> 2;        // 0..63
    const int p  = tid & 3;         // 0..3
    const int ws = p << 4;

    float acc[16];
    // ---- stage 1: 5x5 from global ----
    {
        const float bv = sb[0];
        #pragma unroll
        for (int q = 0; q < 16; ++q) acc[q] = bv;
    }
    {
        const float* xp = x + (size_t)blockIdx.x * PLANE;
        #pragma unroll
        for (int i = 0; i < 5; ++i) {
            const int rt = h + i - 2;
            float f[24];
            #pragma unroll
            for (int q = 0; q < 6; ++q) {
                const int c0 = ws - 4 + 4 * q;
                float4 v = make_float4(0.f, 0.f, 0.f, 0.f);
                if ((unsigned)rt < 64u && (unsigned)c0 <= 60u)
                    v = *reinterpret_cast<const float4*>(xp + rt * HW + c0);
                f[4*q+0] = v.x; f[4*q+1] = v.y; f[4*q+2] = v.z; f[4*q+3] = v.w;
            }
            #pragma unroll
            for (int j = 0; j < 5; ++j) {
                const float wg = sw0[i * 5 + j];
                #pragma unroll
                for (int q = 0; q < 16; ++q) acc[q] += f[q + j + 2] * wg;
            }
        }
    }
    // ---- write initial row (h+10), swizzled ----
    {
        const int R   = h + IP_R0;
        const int swz = (R & 7) << 4;
        char* rb = ipb + R * IP_ROWB;
        #pragma unroll
        for (int q = 0; q < 4; ++q)
            *reinterpret_cast<float4*>(rb + ((48 + 64 * p + 16 * q) ^ swz)) =
                make_float4(acc[4*q], acc[4*q+1], acc[4*q+2], acc[4*q+3]);
    }
    __syncthreads();

    // ---- horizontal 21-tap ----
    {
        const float bv = sb[1];
        #pragma unroll
        for (int q = 0; q < 16; ++q) acc[q] = bv;
    }
    {
        const int R   = h + IP_R0;
        const int swz = (R & 7) << 4;
        const char* rb = ipb + R * IP_ROWB;
        float f[40];
        #pragma unroll
        for (int q = 0; q < 10; ++q) {
            const float4 v = *reinterpret_cast<const float4*>(rb + ((64 * p + 16 * q) ^ swz));
            f[4*q+0] = v.x; f[4*q+1] = v.y; f[4*q+2] = v.z; f[4*q+3] = v.w;
        }
        #pragma unroll
        for (int j = 0; j < 21; ++j) {
            const float wg = swh[j];
            #pragma unroll
            for (int q = 0; q < 16; ++q) acc[q] += f[2 + q + j] * wg;
        }
    }
    // ---- vertical 21-tap (packed f32x2 accum) ----
    f32x2 vacc[8];
    #pragma unroll
    for (int q = 0; q < 8; ++q) vacc[q] = (f32x2){0.f, 0.f};
    #pragma unroll
    for (int i = 0; i < 21; ++i) {
        const float wg = swv[i];
        const f32x2 w2 = (f32x2){wg, wg};
        const int R   = h + i;
        const int swz = (R & 7) << 4;
        const char* rb = ipb + R * IP_ROWB;
        #pragma unroll
        for (int q = 0; q < 4; ++q) {
            const float4 v = *reinterpret_cast<const float4*>(rb + ((48 + 64 * p + 16 * q) ^ swz));
            f32x2 lo; lo.x = v.x; lo.y = v.y;
            f32x2 hi; hi.x = v.z; hi.y = v.w;
            vacc[2*q]   += lo * w2;
            vacc[2*q+1] += hi * w2;
        }
    }
    // ---- store spatial bf16, [c][(n,px)] layout ----
    {
        unsigned short u[16];
        #pragma unroll
        for (int q = 0; q < 16; ++q)
            u[q] = f2bf(acc[q] + vacc[q >> 1][q & 1]);
        unsigned short* op = spB + ((size_t)c * NBATCH + n) * PLANE + h * HW + ws;
        *reinterpret_cast<short8v*>(op)     = *reinterpret_cast<short8v*>(&u[0]);
        *reinterpret_cast<short8v*>(op + 8) = *reinterpret_cast<short8v*>(&u[8]);
    }
}

// ---------------- wa fp32 -> bf16 ----------------
__global__ __launch_bounds__(256)
void wa_cvt(const float* __restrict__ wa, unsigned short* __restrict__ waB)
{
    const int i = blockIdx.x * 256 + threadIdx.x;   // 36864 float4s
    const float4 v = reinterpret_cast<const float4*>(wa)[i];
    ushort4 o;
    o.x = f2bf(v.x); o.y = f2bf(v.y); o.z = f2bf(v.z); o.w = f2bf(v.w);
    reinterpret_cast<ushort4*>(waB)[i] = o;
}

// ---------------- 1x1 conv as bf16 MFMA GEMM (unchanged) ----------------
__global__ __launch_bounds__(256)
void pw_mfma(const unsigned short* __restrict__ spB,
             const unsigned short* __restrict__ waB,
             const float* __restrict__ ba, float* __restrict__ out)
{
    __shared__ unsigned short As[128 * 64];
    __shared__ unsigned short Bs[128 * 64];

    const int tid  = threadIdx.x;
    const int lane = tid & 63;
    const int wid  = tid >> 6;
    const int wrow = wid >> 1;
    const int wcol = wid & 1;

    const int co0  = blockIdx.y * 128;
    const int col0 = blockIdx.x * 128;

    f32x4 acc[4][4];
    #pragma unroll
    for (int m = 0; m < 4; ++m)
        #pragma unroll
        for (int nn = 0; nn < 4; ++nn) acc[m][nn] = (f32x4){0.f, 0.f, 0.f, 0.f};

    const char* waBb = (const char*)waB;

    for (int kt = 0; kt < 6; ++kt) {
        #pragma unroll
        for (int q = 0; q < 4; ++q) {
            const int L     = (wid * 4 + q) * 1024 + lane * 16;
            const int row   = L >> 7;
            const int kbyte = (L & 127) ^ ((row & 7) << 4);
            const void* src = (const void*)(waBb + (size_t)(co0 + row) * 768 + kt * 128 + kbyte);
            __builtin_amdgcn_global_load_lds(
                (const __attribute__((address_space(1))) void*)src,
                (__attribute__((address_space(3))) void*)((char*)As + (wid * 4 + q) * 1024),
                16, 0, 0);
        }

        #pragma unroll
        for (int j = 0; j < 2; ++j) {
            const int kloc  = j * 32 + 2 * (tid >> 4);
            const int cbase = 8 * (tid & 15);
            const unsigned int* gp =
                (const unsigned int*)(spB + (size_t)(kt * 64 + kloc) * NTOT + col0 + cbase);
            unsigned int g0[4], g1[4];
            *(uint4*)g0 = *(const uint4*)gp;
            *(uint4*)g1 = *(const uint4*)(gp + NTOT / 2);
            #pragma unroll
            for (int r = 0; r < 8; ++r) {
                const unsigned int w0v = g0[r >> 1], w1v = g1[r >> 1];
                const unsigned int lo = (r & 1) ? (w0v >> 16) : (w0v & 0xffffu);
                const unsigned int hi = (r & 1) ? (w1v >> 16) : (w1v & 0xffffu);
                const unsigned int val = lo | (hi << 16);
                const int colL = cbase + r;
                const int s    = (r ^ (tid & 7)) & 7;
                const int byte = colL * 128 + ((kloc * 2) ^ (s << 4));
                *(unsigned int*)((char*)Bs + byte) = val;
            }
        }
        __syncthreads();

        #pragma unroll
        for (int kk = 0; kk < 2; ++kk) {
            short8v aF[4], bF[4];
            const int kbyte = kk * 64 + (lane >> 4) * 16;
            #pragma unroll
            for (int m = 0; m < 4; ++m) {
                const int row = wrow * 64 + m * 16 + (lane & 15);
                aF[m] = *(const short8v*)((const char*)As + row * 128 + (kbyte ^ ((row & 7) << 4)));
            }
            #pragma unroll
            for (int nn = 0; nn < 4; ++nn) {
                const int col = wcol * 64 + nn * 16 + (lane & 15);
                const int s   = ((col & 7) ^ ((col >> 3) & 7)) << 4;
                bF[nn] = *(const short8v*)((const char*)Bs + col * 128 + (kbyte ^ s));
            }
            #pragma unroll
            for (int m = 0; m < 4; ++m)
                #pragma unroll
                for (int nn = 0; nn < 4; ++nn)
                    acc[m][nn] = __builtin_amdgcn_mfma_f32_16x16x32_bf16(
                        aF[m], bF[nn], acc[m][nn], 0, 0, 0);
        }
        __syncthreads();
    }

    const int nb  = col0 >> 12;
    const int px0 = col0 & 4095;
    #pragma unroll
    for (int m = 0; m < 4; ++m) {
        #pragma unroll
        for (int r = 0; r < 4; ++r) {
            const int co = co0 + wrow * 64 + m * 16 + 4 * (lane >> 4) + r;
            const float bv = ba[co];
            float* orow = out + ((size_t)(nb * CCH + co)) * PLANE + px0 + wcol * 64 + (lane & 15);
            #pragma unroll
            for (int nn = 0; nn < 4; ++nn)
                orow[nn * 16] = acc[m][nn][r] + bv;
        }
    }
}

extern "C" void kernel_launch(void* const* d_in, const int* in_sizes, int n_in,
                              void* d_out, int out_size, void* d_ws, size_t ws_size,
                              hipStream_t stream)
{
    const float* x  = (const float*)d_in[0];
    const float* w0 = (const float*)d_in[1];
    const float* b0 = (const float*)d_in[2];
    const float* w1 = (const float*)d_in[3];
    const float* b1 = (const float*)d_in[4];
    const float* w2 = (const float*)d_in[5];
    const float* b2 = (const float*)d_in[6];
    const float* w3 = (const float*)d_in[7];
    const float* b3 = (const float*)d_in[8];
    const float* w4 = (const float*)d_in[9];
    const float* b4 = (const float*)d_in[10];
    const float* w5 = (const float*)d_in[11];
    const float* b5 = (const float*)d_in[12];
    const float* w6 = (const float*)d_in[13];
    const float* b6 = (const float*)d_in[14];
    const float* wa = (const float*)d_in[15];
    const float* ba = (const float*)d_in[16];
    float* out = (float*)d_out;

    unsigned short* spB = (unsigned short*)d_ws;                       // 50,331,648 B
    unsigned short* waB = (unsigned short*)((char*)d_ws + 50331648);   // 294,912 B

    wa_cvt<<<dim3(36864 / 256), 256, 0, stream>>>(wa, waB);
    dw_fused<<<dim3(NBATCH * CCH), 256, 0, stream>>>(
        x, w0, b0, w1, b1, w2, b2, w3, b3, w4, b4, w5, b5, w6, b6, spB);
    pw_mfma<<<dim3(NTOT / 128, CCH / 128), 256, 0, stream>>>(spB, waB, ba, out);
}

// Round 5
// 166.614 us; speedup vs baseline: 1.6938x; 1.6938x over previous
//
#include <hip/hip_runtime.h>
#include <cstdint>

#define NBATCH 16
#define CCH    384
#define HW     64
#define PLANE  (HW*HW)
#define NTOT   (NBATCH*PLANE)   // 65536 GEMM columns

typedef __attribute__((ext_vector_type(8))) short short8v;
typedef __attribute__((ext_vector_type(4))) float f32x4;

static __device__ __forceinline__ unsigned short f2bf(float f) {
    unsigned int x = __float_as_uint(f);
    unsigned int r = (x + 0x7fffu + ((x >> 16) & 1u)) >> 16;   // RTN-even
    return (unsigned short)r;
}

// ---------------- fused depthwise kernel v3b ----------------
// block = one (n,c) 64x64 plane, 256 threads.
//   phase 0: stage x into xs (68x68, +-2 halo); zero ip_c vertical halo
//   phase 1: 5x5 from xs -> acc[16]; write acc TRANSPOSED into ip_c[w][h+10]
//   phase 2: horizontal 21-tap fully in registers (lane+-1 shuffles)
//   phase 3: column role (w=tid>>2): vertical 21-tap from ip_c contiguous
//            window (9x b128), write vres[w][h] (col-major, aliases xs)
//   phase 4: row role reads vres (16x b32, 2-way free), combine, bf16 store
// ip_c swizzle: ADDITIVE rotation off=(hs<<2)+64*((w>>4)&1) mod IPC_SB.
//   (XOR-64 on a 368B row overflows for hs>=76 -- that was round 4's bug.)
//   No wrap in phase-1 writes (hs<=73): odd-p groups land exactly +16 banks
//   -> perfect 2-way. Phase-3 b128 reads stay uniform (7*wv slot spread).
#define XS_S   68                 // 17 f4 granules (odd -> conflict-free b128)
#define IPC_SB 368                // ip_c row stride bytes (92 floats, 23 granules)
#define VR_SB  272                // vres row stride bytes (68 floats, 17 granules)

static __device__ __forceinline__ int ipc_byte(int w, int hs) {
    int off = (hs << 2) + (((w >> 4) & 1) << 6);
    if (off >= IPC_SB) off -= IPC_SB;
    return w * IPC_SB + off;
}
static __device__ __forceinline__ int vres_byte(int w, int h) {
    return w * VR_SB + ((h << 2) ^ (((w >> 4) & 1) << 6));   // range-safe: h<=63
}

__global__ __launch_bounds__(256)
void dw_fused(const float* __restrict__ x,
              const float* __restrict__ w0, const float* __restrict__ b0,
              const float* __restrict__ w1, const float* __restrict__ b1,
              const float* __restrict__ w2, const float* __restrict__ b2,
              const float* __restrict__ w3, const float* __restrict__ b3,
              const float* __restrict__ w4, const float* __restrict__ b4,
              const float* __restrict__ w5, const float* __restrict__ b5,
              const float* __restrict__ w6, const float* __restrict__ b6,
              unsigned short* __restrict__ spB)
{
    __shared__ float xsv[XS_S * XS_S];       // xs (ph 0-1) / vres (ph 3-4): 18496 B
    __shared__ char  ipcb[64 * IPC_SB];      // transposed initial: 23552 B
    __shared__ float sw0[25];
    __shared__ float swh[21];
    __shared__ float swv[21];
    __shared__ float sb[2];

    const int tid = threadIdx.x;
    const int n   = blockIdx.x / CCH;
    const int c   = blockIdx.x % CCH;

    // ---- weights (combined centered 1-D kernels) ----
    if (tid < 25) {
        sw0[tid] = w0[c * 25 + tid];
    } else if (tid < 46) {                    // horizontal: w5(21)+w3(11)+w1(7)
        const int d = tid - 25, dj = d - 10;
        float v = w5[c * 21 + d];
        if (dj >= -5 && dj <= 5) v += w3[c * 11 + dj + 5];
        if (dj >= -3 && dj <= 3) v += w1[c * 7  + dj + 3];
        swh[d] = v;
    } else if (tid < 67) {                    // vertical: w6(21)+w4(11)+w2(7)
        const int d = tid - 46, di = d - 10;
        float v = w6[c * 21 + d];
        if (di >= -5 && di <= 5) v += w4[c * 11 + di + 5];
        if (di >= -3 && di <= 3) v += w2[c * 7  + di + 3];
        swv[d] = v;
    } else if (tid == 67) {
        sb[0] = b0[c];
    } else if (tid == 68) {
        sb[1] = b1[c] + b2[c] + b3[c] + b4[c] + b5[c] + b6[c];
    }

    // ---- phase 0a: zero ip_c vertical halo (hs 0..11 and 72..83, all w) ----
    {
        const float4 z = make_float4(0.f, 0.f, 0.f, 0.f);
        #pragma unroll
        for (int rep = 0; rep < 2; ++rep) {
            const int idx = tid + rep * 256;
            if (idx < 384) {
                const int w  = idx / 6;
                const int gi = idx - w * 6;
                const int g  = (gi < 3) ? gi : gi + 15;          // granules 0,1,2,18,19,20
                *reinterpret_cast<float4*>(ipcb + ipc_byte(w, g << 2)) = z;
            }
        }
    }
    // ---- phase 0b: stage x with +-2 zero halo ----
    {
        const float* xp = x + (size_t)blockIdx.x * PLANE;
        for (int i = tid; i < XS_S * XS_S; i += 256) {
            const int r = i / XS_S, cc = i - r * XS_S;
            const int gh = r - 2, gw = cc - 2;
            float v = 0.f;
            if ((unsigned)gh < (unsigned)HW && (unsigned)gw < (unsigned)HW)
                v = xp[gh * HW + gw];
            xsv[i] = v;
        }
    }
    __syncthreads();   // B1

    const int h  = tid >> 2;        // 0..63
    const int p  = tid & 3;         // 0..3
    const int ws = p << 4;

    // ---- phase 1: 5x5 from xs ----
    float acc[16];
    {
        const float bv = sb[0];
        #pragma unroll
        for (int q = 0; q < 16; ++q) acc[q] = bv;
    }
    #pragma unroll
    for (int i = 0; i < 5; ++i) {
        float f[20];
        const float* row = &xsv[(h + i) * XS_S + ws];
        #pragma unroll
        for (int q = 0; q < 5; ++q) {
            const float4 v = *reinterpret_cast<const float4*>(row + 4 * q);
            f[4*q+0] = v.x; f[4*q+1] = v.y; f[4*q+2] = v.z; f[4*q+3] = v.w;
        }
        #pragma unroll
        for (int j = 0; j < 5; ++j) {
            const float wg = sw0[i * 5 + j];
            #pragma unroll
            for (int q = 0; q < 16; ++q) acc[q] += f[q + j] * wg;
        }
    }
    // transposed write: initial[h][ws+k] -> ip_c[ws+k][h+10]  (hs<=73: no wrap)
    #pragma unroll
    for (int k = 0; k < 16; ++k)
        *reinterpret_cast<float*>(ipcb + ipc_byte(ws + k, h + 10)) = acc[k];

    // ---- phase 2: horizontal 21-tap in registers ----
    float L[10], R[10];
    #pragma unroll
    for (int j = 0; j < 10; ++j) {
        L[j] = __shfl_up(acc[6 + j], 1);
        R[j] = __shfl_down(acc[j], 1);
    }
    if (p == 0) {
        #pragma unroll
        for (int j = 0; j < 10; ++j) L[j] = 0.f;
    }
    if (p == 3) {
        #pragma unroll
        for (int j = 0; j < 10; ++j) R[j] = 0.f;
    }
    float hacc[16];
    {
        const float bv = sb[1];
        #pragma unroll
        for (int q = 0; q < 16; ++q) hacc[q] = bv;
    }
    #pragma unroll
    for (int j = 0; j < 21; ++j) {
        const float wg = swh[j];
        #pragma unroll
        for (int q = 0; q < 16; ++q) {
            const int t = q + j;               // 0..35, compile-time
            const float fv = (t < 10) ? L[t] : ((t < 26) ? acc[t - 10] : R[t - 26]);
            hacc[q] += fv * wg;
        }
    }
    __syncthreads();   // B2: ip_c complete, xs dead (vres reuses it)

    // ---- phase 3: vertical 21-tap, column role ----
    {
        char* vrb = reinterpret_cast<char*>(xsv);
        const int wv = tid >> 2;               // 0..63
        const int h0 = (tid & 3) << 4;         // 0,16,32,48
        float g[36];
        #pragma unroll
        for (int q = 0; q < 9; ++q) {
            const float4 v = *reinterpret_cast<const float4*>(ipcb + ipc_byte(wv, h0 + 4 * q));
            g[4*q+0] = v.x; g[4*q+1] = v.y; g[4*q+2] = v.z; g[4*q+3] = v.w;
        }
        float vac[16];
        #pragma unroll
        for (int q = 0; q < 16; ++q) vac[q] = 0.f;
        #pragma unroll
        for (int i = 0; i < 21; ++i) {
            const float wg = swv[i];
            #pragma unroll
            for (int q = 0; q < 16; ++q) vac[q] += g[q + i] * wg;
        }
        #pragma unroll
        for (int q = 0; q < 4; ++q)
            *reinterpret_cast<float4*>(vrb + vres_byte(wv, h0 + 4 * q)) =
                make_float4(vac[4*q], vac[4*q+1], vac[4*q+2], vac[4*q+3]);
    }
    __syncthreads();   // B3

    // ---- phase 4: combine + bf16 store ----
    {
        const char* vrb = reinterpret_cast<const char*>(xsv);
        unsigned short u[16];
        #pragma unroll
        for (int k = 0; k < 16; ++k) {
            const float vv = *reinterpret_cast<const float*>(vrb + vres_byte(ws + k, h));
            u[k] = f2bf(hacc[k] + vv);
        }
        unsigned short* op = spB + ((size_t)c * NBATCH + n) * PLANE + h * HW + ws;
        *reinterpret_cast<short8v*>(op)     = *reinterpret_cast<short8v*>(&u[0]);
        *reinterpret_cast<short8v*>(op + 8) = *reinterpret_cast<short8v*>(&u[8]);
    }
}

// ---------------- wa fp32 -> bf16 ----------------
__global__ __launch_bounds__(256)
void wa_cvt(const float* __restrict__ wa, unsigned short* __restrict__ waB)
{
    const int i = blockIdx.x * 256 + threadIdx.x;   // 36864 float4s
    const float4 v = reinterpret_cast<const float4*>(wa)[i];
    ushort4 o;
    o.x = f2bf(v.x); o.y = f2bf(v.y); o.z = f2bf(v.z); o.w = f2bf(v.w);
    reinterpret_cast<ushort4*>(waB)[i] = o;
}

// ---------------- 1x1 conv as bf16 MFMA GEMM (unchanged, ~5us) ----------------
__global__ __launch_bounds__(256)
void pw_mfma(const unsigned short* __restrict__ spB,
             const unsigned short* __restrict__ waB,
             const float* __restrict__ ba, float* __restrict__ out)
{
    __shared__ unsigned short As[128 * 64];
    __shared__ unsigned short Bs[128 * 64];

    const int tid  = threadIdx.x;
    const int lane = tid & 63;
    const int wid  = tid >> 6;
    const int wrow = wid >> 1;
    const int wcol = wid & 1;

    const int co0  = blockIdx.y * 128;
    const int col0 = blockIdx.x * 128;

    f32x4 acc[4][4];
    #pragma unroll
    for (int m = 0; m < 4; ++m)
        #pragma unroll
        for (int nn = 0; nn < 4; ++nn) acc[m][nn] = (f32x4){0.f, 0.f, 0.f, 0.f};

    const char* waBb = (const char*)waB;

    for (int kt = 0; kt < 6; ++kt) {
        #pragma unroll
        for (int q = 0; q < 4; ++q) {
            const int L     = (wid * 4 + q) * 1024 + lane * 16;
            const int row   = L >> 7;
            const int kbyte = (L & 127) ^ ((row & 7) << 4);
            const void* src = (const void*)(waBb + (size_t)(co0 + row) * 768 + kt * 128 + kbyte);
            __builtin_amdgcn_global_load_lds(
                (const __attribute__((address_space(1))) void*)src,
                (__attribute__((address_space(3))) void*)((char*)As + (wid * 4 + q) * 1024),
                16, 0, 0);
        }

        #pragma unroll
        for (int j = 0; j < 2; ++j) {
            const int kloc  = j * 32 + 2 * (tid >> 4);
            const int cbase = 8 * (tid & 15);
            const unsigned int* gp =
                (const unsigned int*)(spB + (size_t)(kt * 64 + kloc) * NTOT + col0 + cbase);
            unsigned int g0[4], g1[4];
            *(uint4*)g0 = *(const uint4*)gp;
            *(uint4*)g1 = *(const uint4*)(gp + NTOT / 2);
            #pragma unroll
            for (int r = 0; r < 8; ++r) {
                const unsigned int w0v = g0[r >> 1], w1v = g1[r >> 1];
                const unsigned int lo = (r & 1) ? (w0v >> 16) : (w0v & 0xffffu);
                const unsigned int hi = (r & 1) ? (w1v >> 16) : (w1v & 0xffffu);
                const unsigned int val = lo | (hi << 16);
                const int colL = cbase + r;
                const int s    = (r ^ (tid & 7)) & 7;
                const int byte = colL * 128 + ((kloc * 2) ^ (s << 4));
                *(unsigned int*)((char*)Bs + byte) = val;
            }
        }
        __syncthreads();

        #pragma unroll
        for (int kk = 0; kk < 2; ++kk) {
            short8v aF[4], bF[4];
            const int kbyte = kk * 64 + (lane >> 4) * 16;
            #pragma unroll
            for (int m = 0; m < 4; ++m) {
                const int row = wrow * 64 + m * 16 + (lane & 15);
                aF[m] = *(const short8v*)((const char*)As + row * 128 + (kbyte ^ ((row & 7) << 4)));
            }
            #pragma unroll
            for (int nn = 0; nn < 4; ++nn) {
                const int col = wcol * 64 + nn * 16 + (lane & 15);
                const int s   = ((col & 7) ^ ((col >> 3) & 7)) << 4;
                bF[nn] = *(const short8v*)((const char*)Bs + col * 128 + (kbyte ^ s));
            }
            #pragma unroll
            for (int m = 0; m < 4; ++m)
                #pragma unroll
                for (int nn = 0; nn < 4; ++nn)
                    acc[m][nn] = __builtin_amdgcn_mfma_f32_16x16x32_bf16(
                        aF[m], bF[nn], acc[m][nn], 0, 0, 0);
        }
        __syncthreads();
    }

    const int nb  = col0 >> 12;
    const int px0 = col0 & 4095;
    #pragma unroll
    for (int m = 0; m < 4; ++m) {
        #pragma unroll
        for (int r = 0; r < 4; ++r) {
            const int co = co0 + wrow * 64 + m * 16 + 4 * (lane >> 4) + r;
            const float bv = ba[co];
            float* orow = out + ((size_t)(nb * CCH + co)) * PLANE + px0 + wcol * 64 + (lane & 15);
            #pragma unroll
            for (int nn = 0; nn < 4; ++nn)
                orow[nn * 16] = acc[m][nn][r] + bv;
        }
    }
}

extern "C" void kernel_launch(void* const* d_in, const int* in_sizes, int n_in,
                              void* d_out, int out_size, void* d_ws, size_t ws_size,
                              hipStream_t stream)
{
    const float* x  = (const float*)d_in[0];
    const float* w0 = (const float*)d_in[1];
    const float* b0 = (const float*)d_in[2];
    const float* w1 = (const float*)d_in[3];
    const float* b1 = (const float*)d_in[4];
    const float* w2 = (const float*)d_in[5];
    const float* b2 = (const float*)d_in[6];
    const float* w3 = (const float*)d_in[7];
    const float* b3 = (const float*)d_in[8];
    const float* w4 = (const float*)d_in[9];
    const float* b4 = (const float*)d_in[10];
    const float* w5 = (const float*)d_in[11];
    const float* b5 = (const float*)d_in[12];
    const float* w6 = (const float*)d_in[13];
    const float* b6 = (const float*)d_in[14];
    const float* wa = (const float*)d_in[15];
    const float* ba = (const float*)d_in[16];
    float* out = (float*)d_out;

    unsigned short* spB = (unsigned short*)d_ws;                       // 50,331,648 B
    unsigned short* waB = (unsigned short*)((char*)d_ws + 50331648);   // 294,912 B

    wa_cvt<<<dim3(36864 / 256), 256, 0, stream>>>(wa, waB);
    dw_fused<<<dim3(NBATCH * CCH), 256, 0, stream>>>(
        x, w0, b0, w1, b1, w2, b2, w3, b3, w4, b4, w5, b5, w6, b6, spB);
    pw_mfma<<<dim3(NTOT / 128, CCH / 128), 256, 0, stream>>>(spB, waB, ba, out);
}

// Round 6
// 141.032 us; speedup vs baseline: 2.0011x; 1.1814x over previous
//
#include <hip/hip_runtime.h>
#include <cstdint>

#define NBATCH 16
#define CCH    384
#define HW     64
#define PLANE  (HW*HW)
#define NTOT   (NBATCH*PLANE)   // 65536 GEMM columns

typedef __attribute__((ext_vector_type(8))) short short8v;
typedef __attribute__((ext_vector_type(4))) float f32x4;

static __device__ __forceinline__ unsigned short f2bf(float f) {
    unsigned int x = __float_as_uint(f);
    unsigned int r = (x + 0x7fffu + ((x >> 16) & 1u)) >> 16;   // RTN-even
    return (unsigned short)r;
}
static __device__ __forceinline__ float bf2f(unsigned int lo16) {
    return __uint_as_float(lo16 << 16);
}

// ---------------- fused depthwise kernel v4 ----------------
// block = one (n,c) 64x64 plane, 256 threads; thread roles:
//   row role  (h = tid>>2, ws = (tid&3)*16)  for 5x5, H-conv, final store
//   col role  (wv = tid>>2, h0 = (tid&3)*16) for V-conv
// LDS: ONE 8 KB buffer tb[64*128], used twice:
//   scheme C (phases 1-3): ipT[w][h] bf16,  byte = w*128 + ((2h + 16*rC(w)) & 127),
//       rC(w) = 2*(w>>4) + (w&7)
//   scheme D (phases 4-5): vT[h][w] bf16,   byte = h*128 + ((2w + 16*rD(h)) & 127),
//       rD(h) = 2*(h>>4) + (h&7)
// Both: rows exactly 128 B, rotations multiples of 16 B, closed under &127
// (round-4 lesson: swizzle must be bijective within the row). Scalar b16
// writes land on 32 distinct words (h/w-pairs share a word, different bytes
// -> merged); b128 reads uniform over the 8 granule slots.
// Vertical zero-padding is NOT stored: the 48-value read window is fetched
// as 6x16B blocks, each fully inside [0,64) or fully outside (0/64 are
// multiples of 8), so whole blocks are predicated to zero.

__global__ __launch_bounds__(256)
void dw_fused(const float* __restrict__ x,
              const float* __restrict__ w0, const float* __restrict__ b0,
              const float* __restrict__ w1, const float* __restrict__ b1,
              const float* __restrict__ w2, const float* __restrict__ b2,
              const float* __restrict__ w3, const float* __restrict__ b3,
              const float* __restrict__ w4, const float* __restrict__ b4,
              const float* __restrict__ w5, const float* __restrict__ b5,
              const float* __restrict__ w6, const float* __restrict__ b6,
              unsigned short* __restrict__ spB)
{
    __shared__ char  tb[64 * 128];       // 8192 B, dual-use (ipT then vT)
    __shared__ float sw0[25];
    __shared__ float swh[21];
    __shared__ float swv[21];
    __shared__ float sb[2];

    const int tid = threadIdx.x;
    const int n   = blockIdx.x / CCH;
    const int c   = blockIdx.x % CCH;

    // ---- weights (combined centered 1-D kernels) ----
    if (tid < 25) {
        sw0[tid] = w0[c * 25 + tid];
    } else if (tid < 46) {                    // horizontal: w5(21)+w3(11)+w1(7)
        const int d = tid - 25, dj = d - 10;
        float v = w5[c * 21 + d];
        if (dj >= -5 && dj <= 5) v += w3[c * 11 + dj + 5];
        if (dj >= -3 && dj <= 3) v += w1[c * 7  + dj + 3];
        swh[d] = v;
    } else if (tid < 67) {                    // vertical: w6(21)+w4(11)+w2(7)
        const int d = tid - 46, di = d - 10;
        float v = w6[c * 21 + d];
        if (di >= -5 && di <= 5) v += w4[c * 11 + di + 5];
        if (di >= -3 && di <= 3) v += w2[c * 7  + di + 3];
        swv[d] = v;
    } else if (tid == 67) {
        sb[0] = b0[c];
    } else if (tid == 68) {
        sb[1] = b1[c] + b2[c] + b3[c] + b4[c] + b5[c] + b6[c];
    }
    __syncthreads();   // B1: weights visible

    const int h  = tid >> 2;        // 0..63
    const int p  = tid & 3;         // 0..3
    const int ws = p << 4;

    // ---- phase 1: 5x5 direct from global (plane is L1-resident) ----
    float acc[16];
    {
        const float bv = sb[0];
        #pragma unroll
        for (int q = 0; q < 16; ++q) acc[q] = bv;
    }
    {
        const float* xp = x + (size_t)blockIdx.x * PLANE;
        #pragma unroll
        for (int i = 0; i < 5; ++i) {
            const int rt = h + i - 2;
            float f[24];
            #pragma unroll
            for (int q = 0; q < 6; ++q) {
                const int c0 = ws - 4 + 4 * q;
                float4 v = make_float4(0.f, 0.f, 0.f, 0.f);
                if ((unsigned)rt < 64u && (unsigned)c0 <= 60u)
                    v = *reinterpret_cast<const float4*>(xp + rt * HW + c0);
                f[4*q+0] = v.x; f[4*q+1] = v.y; f[4*q+2] = v.z; f[4*q+3] = v.w;
            }
            #pragma unroll
            for (int j = 0; j < 5; ++j) {
                const float wg = sw0[i * 5 + j];
                #pragma unroll
                for (int q = 0; q < 16; ++q) acc[q] += f[q + j + 2] * wg;
            }
        }
    }
    // transposed bf16 write: initial[h][ws+k] -> ipT[ws+k][h]   (scheme C)
    #pragma unroll
    for (int k = 0; k < 16; ++k) {
        const int w   = ws + k;
        const int rC  = 2 * p + (k & 7);          // = 2*(w>>4) + (w&7)
        const int off = (2 * h + 16 * rC) & 127;
        *reinterpret_cast<unsigned short*>(tb + w * 128 + off) = f2bf(acc[k]);
    }

    // ---- phase 2: horizontal 21-tap in registers (verified r5 pattern) ----
    float L[10], R[10];
    #pragma unroll
    for (int j = 0; j < 10; ++j) {
        L[j] = __shfl_up(acc[6 + j], 1);
        R[j] = __shfl_down(acc[j], 1);
    }
    if (p == 0) {
        #pragma unroll
        for (int j = 0; j < 10; ++j) L[j] = 0.f;
    }
    if (p == 3) {
        #pragma unroll
        for (int j = 0; j < 10; ++j) R[j] = 0.f;
    }
    float hacc[16];
    {
        const float bv = sb[1];
        #pragma unroll
        for (int q = 0; q < 16; ++q) hacc[q] = bv;
    }
    #pragma unroll
    for (int j = 0; j < 21; ++j) {
        const float wg = swh[j];
        #pragma unroll
        for (int q = 0; q < 16; ++q) {
            const int t = q + j;               // 0..35, compile-time
            const float fv = (t < 10) ? L[t] : ((t < 26) ? acc[t - 10] : R[t - 26]);
            hacc[q] += fv * wg;
        }
    }
    __syncthreads();   // B2: ipT complete

    // ---- phase 3: vertical 21-tap, column role, window from ipT ----
    float vcol[16];
    {
        const int wv  = tid >> 2;              // 0..63
        const int p2  = tid & 3;
        const int h0  = p2 << 4;               // 0,16,32,48
        const int rCv = 2 * (wv >> 4) + (wv & 7);
        uint4 gv[6];
        #pragma unroll
        for (int m = 0; m < 6; ++m) {
            const int hs = h0 - 16 + 8 * m;    // window block start (mult of 8)
            if (hs >= 0 && hs <= 56) {
                const int off = (32 * p2 + 96 + 16 * m + 16 * rCv) & 127;
                gv[m] = *reinterpret_cast<const uint4*>(tb + wv * 128 + off);
            } else {
                gv[m] = make_uint4(0u, 0u, 0u, 0u);
            }
        }
        // unpack window elements e=6..41 (tap h = h0-16+e), e compile-time
        float gf[36];
        #pragma unroll
        for (int e = 6; e < 42; ++e) {
            const unsigned int wd =
                (&gv[e >> 3].x)[(e >> 1) & 3];
            gf[e - 6] = (e & 1) ? __uint_as_float(wd & 0xffff0000u) : bf2f(wd & 0xffffu);
        }
        #pragma unroll
        for (int j = 0; j < 16; ++j) vcol[j] = 0.f;
        #pragma unroll
        for (int i = 0; i < 21; ++i) {
            const float wg = swv[i];
            #pragma unroll
            for (int j = 0; j < 16; ++j) vcol[j] += gf[j + i] * wg;
        }
    }
    __syncthreads();   // B3: all scheme-C reads done, tb reusable

    // ---- phase 4: write V result transposed back (scheme D) ----
    {
        const int wv = tid >> 2;
        const int p2 = tid & 3;
        const int h0 = p2 << 4;
        #pragma unroll
        for (int j = 0; j < 16; ++j) {
            const int hh  = h0 + j;
            const int rD  = 2 * p2 + (j & 7);     // = 2*(hh>>4) + (hh&7)
            const int off = (2 * wv + 16 * rD) & 127;
            *reinterpret_cast<unsigned short*>(tb + hh * 128 + off) = f2bf(vcol[j]);
        }
    }
    __syncthreads();   // B4: vT complete

    // ---- phase 5: combine + bf16 store (row role) ----
    {
        const int rD = 2 * (h >> 4) + (h & 7);
        const int o0 = (32 * p + 16 * rD) & 127;
        const int o1 = (32 * p + 16 + 16 * rD) & 127;
        const uint4 va = *reinterpret_cast<const uint4*>(tb + h * 128 + o0);
        const uint4 vb = *reinterpret_cast<const uint4*>(tb + h * 128 + o1);
        unsigned short u[16];
        #pragma unroll
        for (int k = 0; k < 16; ++k) {
            const unsigned int wd = (k < 8) ? (&va.x)[(k >> 1) & 3] : (&vb.x)[(k >> 1) & 3];
            const float vv = (k & 1) ? __uint_as_float(wd & 0xffff0000u) : bf2f(wd & 0xffffu);
            u[k] = f2bf(hacc[k] + vv);
        }
        unsigned short* op = spB + ((size_t)c * NBATCH + n) * PLANE + h * HW + ws;
        *reinterpret_cast<short8v*>(op)     = *reinterpret_cast<short8v*>(&u[0]);
        *reinterpret_cast<short8v*>(op + 8) = *reinterpret_cast<short8v*>(&u[8]);
    }
}

// ---------------- wa fp32 -> bf16 ----------------
__global__ __launch_bounds__(256)
void wa_cvt(const float* __restrict__ wa, unsigned short* __restrict__ waB)
{
    const int i = blockIdx.x * 256 + threadIdx.x;   // 36864 float4s
    const float4 v = reinterpret_cast<const float4*>(wa)[i];
    ushort4 o;
    o.x = f2bf(v.x); o.y = f2bf(v.y); o.z = f2bf(v.z); o.w = f2bf(v.w);
    reinterpret_cast<ushort4*>(waB)[i] = o;
}

// ---------------- 1x1 conv as bf16 MFMA GEMM (unchanged, ~6us) ----------------
__global__ __launch_bounds__(256)
void pw_mfma(const unsigned short* __restrict__ spB,
             const unsigned short* __restrict__ waB,
             const float* __restrict__ ba, float* __restrict__ out)
{
    __shared__ unsigned short As[128 * 64];
    __shared__ unsigned short Bs[128 * 64];

    const int tid  = threadIdx.x;
    const int lane = tid & 63;
    const int wid  = tid >> 6;
    const int wrow = wid >> 1;
    const int wcol = wid & 1;

    const int co0  = blockIdx.y * 128;
    const int col0 = blockIdx.x * 128;

    f32x4 acc[4][4];
    #pragma unroll
    for (int m = 0; m < 4; ++m)
        #pragma unroll
        for (int nn = 0; nn < 4; ++nn) acc[m][nn] = (f32x4){0.f, 0.f, 0.f, 0.f};

    const char* waBb = (const char*)waB;

    for (int kt = 0; kt < 6; ++kt) {
        #pragma unroll
        for (int q = 0; q < 4; ++q) {
            const int L     = (wid * 4 + q) * 1024 + lane * 16;
            const int row   = L >> 7;
            const int kbyte = (L & 127) ^ ((row & 7) << 4);
            const void* src = (const void*)(waBb + (size_t)(co0 + row) * 768 + kt * 128 + kbyte);
            __builtin_amdgcn_global_load_lds(
                (const __attribute__((address_space(1))) void*)src,
                (__attribute__((address_space(3))) void*)((char*)As + (wid * 4 + q) * 1024),
                16, 0, 0);
        }

        #pragma unroll
        for (int j = 0; j < 2; ++j) {
            const int kloc  = j * 32 + 2 * (tid >> 4);
            const int cbase = 8 * (tid & 15);
            const unsigned int* gp =
                (const unsigned int*)(spB + (size_t)(kt * 64 + kloc) * NTOT + col0 + cbase);
            unsigned int g0[4], g1[4];
            *(uint4*)g0 = *(const uint4*)gp;
            *(uint4*)g1 = *(const uint4*)(gp + NTOT / 2);
            #pragma unroll
            for (int r = 0; r < 8; ++r) {
                const unsigned int w0v = g0[r >> 1], w1v = g1[r >> 1];
                const unsigned int lo = (r & 1) ? (w0v >> 16) : (w0v & 0xffffu);
                const unsigned int hi = (r & 1) ? (w1v >> 16) : (w1v & 0xffffu);
                const unsigned int val = lo | (hi << 16);
                const int colL = cbase + r;
                const int s    = (r ^ (tid & 7)) & 7;
                const int byte = colL * 128 + ((kloc * 2) ^ (s << 4));
                *(unsigned int*)((char*)Bs + byte) = val;
            }
        }
        __syncthreads();

        #pragma unroll
        for (int kk = 0; kk < 2; ++kk) {
            short8v aF[4], bF[4];
            const int kbyte = kk * 64 + (lane >> 4) * 16;
            #pragma unroll
            for (int m = 0; m < 4; ++m) {
                const int row = wrow * 64 + m * 16 + (lane & 15);
                aF[m] = *(const short8v*)((const char*)As + row * 128 + (kbyte ^ ((row & 7) << 4)));
            }
            #pragma unroll
            for (int nn = 0; nn < 4; ++nn) {
                const int col = wcol * 64 + nn * 16 + (lane & 15);
                const int s   = ((col & 7) ^ ((col >> 3) & 7)) << 4;
                bF[nn] = *(const short8v*)((const char*)Bs + col * 128 + (kbyte ^ s));
            }
            #pragma unroll
            for (int m = 0; m < 4; ++m)
                #pragma unroll
                for (int nn = 0; nn < 4; ++nn)
                    acc[m][nn] = __builtin_amdgcn_mfma_f32_16x16x32_bf16(
                        aF[m], bF[nn], acc[m][nn], 0, 0, 0);
        }
        __syncthreads();
    }

    const int nb  = col0 >> 12;
    const int px0 = col0 & 4095;
    #pragma unroll
    for (int m = 0; m < 4; ++m) {
        #pragma unroll
        for (int r = 0; r < 4; ++r) {
            const int co = co0 + wrow * 64 + m * 16 + 4 * (lane >> 4) + r;
            const float bv = ba[co];
            float* orow = out + ((size_t)(nb * CCH + co)) * PLANE + px0 + wcol * 64 + (lane & 15);
            #pragma unroll
            for (int nn = 0; nn < 4; ++nn)
                orow[nn * 16] = acc[m][nn][r] + bv;
        }
    }
}

extern "C" void kernel_launch(void* const* d_in, const int* in_sizes, int n_in,
                              void* d_out, int out_size, void* d_ws, size_t ws_size,
                              hipStream_t stream)
{
    const float* x  = (const float*)d_in[0];
    const float* w0 = (const float*)d_in[1];
    const float* b0 = (const float*)d_in[2];
    const float* w1 = (const float*)d_in[3];
    const float* b1 = (const float*)d_in[4];
    const float* w2 = (const float*)d_in[5];
    const float* b2 = (const float*)d_in[6];
    const float* w3 = (const float*)d_in[7];
    const float* b3 = (const float*)d_in[8];
    const float* w4 = (const float*)d_in[9];
    const float* b4 = (const float*)d_in[10];
    const float* w5 = (const float*)d_in[11];
    const float* b5 = (const float*)d_in[12];
    const float* w6 = (const float*)d_in[13];
    const float* b6 = (const float*)d_in[14];
    const float* wa = (const float*)d_in[15];
    const float* ba = (const float*)d_in[16];
    float* out = (float*)d_out;

    unsigned short* spB = (unsigned short*)d_ws;                       // 50,331,648 B
    unsigned short* waB = (unsigned short*)((char*)d_ws + 50331648);   // 294,912 B

    wa_cvt<<<dim3(36864 / 256), 256, 0, stream>>>(wa, waB);
    dw_fused<<<dim3(NBATCH * CCH), 256, 0, stream>>>(
        x, w0, b0, w1, b1, w2, b2, w3, b3, w4, b4, w5, b5, w6, b6, spB);
    pw_mfma<<<dim3(NTOT / 128, CCH / 128), 256, 0, stream>>>(spB, waB, ba, out);
}

// Round 7
// 133.653 us; speedup vs baseline: 2.1116x; 1.0552x over previous
//
#include <hip/hip_runtime.h>
#include <cstdint>

#define NBATCH 16
#define CCH    384
#define HW     64
#define PLANE  (HW*HW)
#define NTOT   (NBATCH*PLANE)   // 65536 GEMM columns

typedef __attribute__((ext_vector_type(8))) short short8v;
typedef __attribute__((ext_vector_type(4))) float f32x4;

static __device__ __forceinline__ unsigned short f2bf(float f) {
    unsigned int x = __float_as_uint(f);
    unsigned int r = (x + 0x7fffu + ((x >> 16) & 1u)) >> 16;   // RTN-even
    return (unsigned short)r;
}

// ---------------- fused depthwise kernel v5: H/V convs on MFMA ----------------
// block = one (n,c) 64x64 plane, 256 threads = 4 waves.
//   B1: per-channel weights -> LDS
//   phase A: build band matrices BV[h][h']=swv[h'-h+10], BH[w][w']=swh[w'-w+10]
//            (bf16, banded; truncation at edges == zero padding);
//            5x5 fp32 direct from global -> initial row segment; write initial
//            bf16 to ipR[h][w] (vectorized) and ipT[w][h] (scalar transposed)
//   B2
//   phase B: per wave (mh = wid): out tiles (mh, nt=0..3), each 16x16:
//            acc = BV@P (A=BV rows, B=ipT) + P@BH^T (A=ipR rows, B=BH), K=64
//            epilogue: + bias_sum, bf16 store to spB
// All LDS arrays are [64 rows][128 B] with scheme-C rotation
//   off(row, kbyte) = (kbyte + 16*(2*(row>>4) + (row&7))) & 127
// -- closed mod 128 (bijective), 16B-aligned, <=2-way banks on every access
// (write+read swizzled identically; round-4 lesson: swizzle must be closed).
// Fragment/access pattern identical to the verified pw_mfma kernel.

static __device__ __forceinline__ int rotC(int row) {
    return 2 * (row >> 4) + (row & 7);
}

__global__ __launch_bounds__(256)
void dw_fused(const float* __restrict__ x,
              const float* __restrict__ w0, const float* __restrict__ b0,
              const float* __restrict__ w1, const float* __restrict__ b1,
              const float* __restrict__ w2, const float* __restrict__ b2,
              const float* __restrict__ w3, const float* __restrict__ b3,
              const float* __restrict__ w4, const float* __restrict__ b4,
              const float* __restrict__ w5, const float* __restrict__ b5,
              const float* __restrict__ w6, const float* __restrict__ b6,
              unsigned short* __restrict__ spB)
{
    __shared__ char ipR[64 * 128];   // initial[h][w]  bf16
    __shared__ char ipT[64 * 128];   // initial[w][h]  bf16
    __shared__ char BVm[64 * 128];   // BV[h][h']      bf16
    __shared__ char BHm[64 * 128];   // BH[w][w']      bf16
    __shared__ float sw0[25];
    __shared__ float swh[21];
    __shared__ float swv[21];
    __shared__ float sb[2];

    const int tid = threadIdx.x;
    const int n   = blockIdx.x / CCH;
    const int c   = blockIdx.x % CCH;

    // ---- per-channel weights (combined centered 1-D kernels) ----
    if (tid < 25) {
        sw0[tid] = w0[c * 25 + tid];
    } else if (tid < 46) {                    // horizontal: w5(21)+w3(11)+w1(7)
        const int d = tid - 25, dj = d - 10;
        float v = w5[c * 21 + d];
        if (dj >= -5 && dj <= 5) v += w3[c * 11 + dj + 5];
        if (dj >= -3 && dj <= 3) v += w1[c * 7  + dj + 3];
        swh[d] = v;
    } else if (tid < 67) {                    // vertical: w6(21)+w4(11)+w2(7)
        const int d = tid - 46, di = d - 10;
        float v = w6[c * 21 + d];
        if (di >= -5 && di <= 5) v += w4[c * 11 + di + 5];
        if (di >= -3 && di <= 3) v += w2[c * 7  + di + 3];
        swv[d] = v;
    } else if (tid == 67) {
        sb[0] = b0[c];
    } else if (tid == 68) {
        sb[1] = b1[c] + b2[c] + b3[c] + b4[c] + b5[c] + b6[c];
    }
    __syncthreads();   // B1

    const int h  = tid >> 2;        // 0..63 (row role / band-matrix row)
    const int p  = tid & 3;         // 0..3
    const int ws = p << 4;

    // ---- phase A1: build band matrices (row i=h, cols ws..ws+15) ----
    {
        unsigned short uv[16], uh[16];
        #pragma unroll
        for (int m = 0; m < 16; ++m) {
            const int d = ws + m - h + 10;
            const bool ok = (unsigned)d < 21u;
            uv[m] = ok ? f2bf(swv[d]) : (unsigned short)0;
            uh[m] = ok ? f2bf(swh[d]) : (unsigned short)0;
        }
        const int rot = rotC(h);
        #pragma unroll
        for (int q = 0; q < 2; ++q) {
            const int off = ((ws << 1) + 16 * q + 16 * rot) & 127;
            *reinterpret_cast<uint4*>(BVm + h * 128 + off) =
                reinterpret_cast<const uint4*>(uv)[q];
            *reinterpret_cast<uint4*>(BHm + h * 128 + off) =
                reinterpret_cast<const uint4*>(uh)[q];
        }
    }

    // ---- phase A2: 5x5 fp32 direct from global (v4-verified) ----
    float acc5[16];
    {
        const float bv = sb[0];
        #pragma unroll
        for (int q = 0; q < 16; ++q) acc5[q] = bv;
    }
    {
        const float* xp = x + (size_t)blockIdx.x * PLANE;
        #pragma unroll
        for (int i = 0; i < 5; ++i) {
            const int rt = h + i - 2;
            float f[24];
            #pragma unroll
            for (int q = 0; q < 6; ++q) {
                const int c0 = ws - 4 + 4 * q;
                float4 v = make_float4(0.f, 0.f, 0.f, 0.f);
                if ((unsigned)rt < 64u && (unsigned)c0 <= 60u)
                    v = *reinterpret_cast<const float4*>(xp + rt * HW + c0);
                f[4*q+0] = v.x; f[4*q+1] = v.y; f[4*q+2] = v.z; f[4*q+3] = v.w;
            }
            #pragma unroll
            for (int j = 0; j < 5; ++j) {
                const float wg = sw0[i * 5 + j];
                #pragma unroll
                for (int q = 0; q < 16; ++q) acc5[q] += f[q + j + 2] * wg;
            }
        }
    }
    // ---- phase A3: write initial bf16 to ipR (vector) and ipT (transposed) ----
    {
        unsigned short u[16];
        #pragma unroll
        for (int k = 0; k < 16; ++k) u[k] = f2bf(acc5[k]);
        const int rot = rotC(h);
        #pragma unroll
        for (int q = 0; q < 2; ++q) {
            const int off = ((ws << 1) + 16 * q + 16 * rot) & 127;
            *reinterpret_cast<uint4*>(ipR + h * 128 + off) =
                reinterpret_cast<const uint4*>(u)[q];
        }
        #pragma unroll
        for (int k = 0; k < 16; ++k) {
            const int w   = ws + k;
            const int off = ((h << 1) + 16 * (2 * p + (k & 7))) & 127;  // rotC(w)
            *reinterpret_cast<unsigned short*>(ipT + w * 128 + off) = u[k];
        }
    }
    __syncthreads();   // B2

    // ---- phase B: MFMA  spatial = BV@P + P@BH^T + bias ----
    {
        const int lane = tid & 63;
        const int wid  = tid >> 6;      // mh: output row tile
        const int l15  = lane & 15;
        const int l16  = lane >> 4;

        const int arow = wid * 16 + l15;
        const int rotA = 16 * (2 * wid + (arow & 7));   // arow>>4 == wid

        short8v aV[2], aH[2];
        #pragma unroll
        for (int kk = 0; kk < 2; ++kk) {
            const int kb  = kk * 64 + l16 * 16;
            const int off = (kb + rotA) & 127;
            aV[kk] = *reinterpret_cast<const short8v*>(BVm + arow * 128 + off);
            aH[kk] = *reinterpret_cast<const short8v*>(ipR + arow * 128 + off);
        }

        const float bv1 = sb[1];
        unsigned short* op = spB + ((size_t)c * NBATCH + n) * PLANE;

        #pragma unroll
        for (int nt = 0; nt < 4; ++nt) {
            const int brow = nt * 16 + l15;
            const int rotB = 16 * (2 * nt + (brow & 7));
            f32x4 acc = (f32x4){0.f, 0.f, 0.f, 0.f};
            #pragma unroll
            for (int kk = 0; kk < 2; ++kk) {
                const int kb  = kk * 64 + l16 * 16;
                const int off = (kb + rotB) & 127;
                const short8v bV = *reinterpret_cast<const short8v*>(ipT + brow * 128 + off);
                const short8v bH = *reinterpret_cast<const short8v*>(BHm + brow * 128 + off);
                acc = __builtin_amdgcn_mfma_f32_16x16x32_bf16(aV[kk], bV, acc, 0, 0, 0);
                acc = __builtin_amdgcn_mfma_f32_16x16x32_bf16(aH[kk], bH, acc, 0, 0, 0);
            }
            // epilogue: C row = wid*16 + 4*l16 + r (from A), col = nt*16 + l15 (from B)
            #pragma unroll
            for (int r = 0; r < 4; ++r) {
                const int hh = wid * 16 + 4 * l16 + r;
                const int ww = nt * 16 + l15;
                op[hh * HW + ww] = f2bf(acc[r] + bv1);
            }
        }
    }
}

// ---------------- wa fp32 -> bf16 ----------------
__global__ __launch_bounds__(256)
void wa_cvt(const float* __restrict__ wa, unsigned short* __restrict__ waB)
{
    const int i = blockIdx.x * 256 + threadIdx.x;   // 36864 float4s
    const float4 v = reinterpret_cast<const float4*>(wa)[i];
    ushort4 o;
    o.x = f2bf(v.x); o.y = f2bf(v.y); o.z = f2bf(v.z); o.w = f2bf(v.w);
    reinterpret_cast<ushort4*>(waB)[i] = o;
}

// ---------------- 1x1 conv as bf16 MFMA GEMM (unchanged, ~6us) ----------------
__global__ __launch_bounds__(256)
void pw_mfma(const unsigned short* __restrict__ spB,
             const unsigned short* __restrict__ waB,
             const float* __restrict__ ba, float* __restrict__ out)
{
    __shared__ unsigned short As[128 * 64];
    __shared__ unsigned short Bs[128 * 64];

    const int tid  = threadIdx.x;
    const int lane = tid & 63;
    const int wid  = tid >> 6;
    const int wrow = wid >> 1;
    const int wcol = wid & 1;

    const int co0  = blockIdx.y * 128;
    const int col0 = blockIdx.x * 128;

    f32x4 acc[4][4];
    #pragma unroll
    for (int m = 0; m < 4; ++m)
        #pragma unroll
        for (int nn = 0; nn < 4; ++nn) acc[m][nn] = (f32x4){0.f, 0.f, 0.f, 0.f};

    const char* waBb = (const char*)waB;

    for (int kt = 0; kt < 6; ++kt) {
        #pragma unroll
        for (int q = 0; q < 4; ++q) {
            const int L     = (wid * 4 + q) * 1024 + lane * 16;
            const int row   = L >> 7;
            const int kbyte = (L & 127) ^ ((row & 7) << 4);
            const void* src = (const void*)(waBb + (size_t)(co0 + row) * 768 + kt * 128 + kbyte);
            __builtin_amdgcn_global_load_lds(
                (const __attribute__((address_space(1))) void*)src,
                (__attribute__((address_space(3))) void*)((char*)As + (wid * 4 + q) * 1024),
                16, 0, 0);
        }

        #pragma unroll
        for (int j = 0; j < 2; ++j) {
            const int kloc  = j * 32 + 2 * (tid >> 4);
            const int cbase = 8 * (tid & 15);
            const unsigned int* gp =
                (const unsigned int*)(spB + (size_t)(kt * 64 + kloc) * NTOT + col0 + cbase);
            unsigned int g0[4], g1[4];
            *(uint4*)g0 = *(const uint4*)gp;
            *(uint4*)g1 = *(const uint4*)(gp + NTOT / 2);
            #pragma unroll
            for (int r = 0; r < 8; ++r) {
                const unsigned int w0v = g0[r >> 1], w1v = g1[r >> 1];
                const unsigned int lo = (r & 1) ? (w0v >> 16) : (w0v & 0xffffu);
                const unsigned int hi = (r & 1) ? (w1v >> 16) : (w1v & 0xffffu);
                const unsigned int val = lo | (hi << 16);
                const int colL = cbase + r;
                const int s    = (r ^ (tid & 7)) & 7;
                const int byte = colL * 128 + ((kloc * 2) ^ (s << 4));
                *(unsigned int*)((char*)Bs + byte) = val;
            }
        }
        __syncthreads();

        #pragma unroll
        for (int kk = 0; kk < 2; ++kk) {
            short8v aF[4], bF[4];
            const int kbyte = kk * 64 + (lane >> 4) * 16;
            #pragma unroll
            for (int m = 0; m < 4; ++m) {
                const int row = wrow * 64 + m * 16 + (lane & 15);
                aF[m] = *(const short8v*)((const char*)As + row * 128 + (kbyte ^ ((row & 7) << 4)));
            }
            #pragma unroll
            for (int nn = 0; nn < 4; ++nn) {
                const int col = wcol * 64 + nn * 16 + (lane & 15);
                const int s   = ((col & 7) ^ ((col >> 3) & 7)) << 4;
                bF[nn] = *(const short8v*)((const char*)Bs + col * 128 + (kbyte ^ s));
            }
            #pragma unroll
            for (int m = 0; m < 4; ++m)
                #pragma unroll
                for (int nn = 0; nn < 4; ++nn)
                    acc[m][nn] = __builtin_amdgcn_mfma_f32_16x16x32_bf16(
                        aF[m], bF[nn], acc[m][nn], 0, 0, 0);
        }
        __syncthreads();
    }

    const int nb  = col0 >> 12;
    const int px0 = col0 & 4095;
    #pragma unroll
    for (int m = 0; m < 4; ++m) {
        #pragma unroll
        for (int r = 0; r < 4; ++r) {
            const int co = co0 + wrow * 64 + m * 16 + 4 * (lane >> 4) + r;
            const float bv = ba[co];
            float* orow = out + ((size_t)(nb * CCH + co)) * PLANE + px0 + wcol * 64 + (lane & 15);
            #pragma unroll
            for (int nn = 0; nn < 4; ++nn)
                orow[nn * 16] = acc[m][nn][r] + bv;
        }
    }
}

extern "C" void kernel_launch(void* const* d_in, const int* in_sizes, int n_in,
                              void* d_out, int out_size, void* d_ws, size_t ws_size,
                              hipStream_t stream)
{
    const float* x  = (const float*)d_in[0];
    const float* w0 = (const float*)d_in[1];
    const float* b0 = (const float*)d_in[2];
    const float* w1 = (const float*)d_in[3];
    const float* b1 = (const float*)d_in[4];
    const float* w2 = (const float*)d_in[5];
    const float* b2 = (const float*)d_in[6];
    const float* w3 = (const float*)d_in[7];
    const float* b3 = (const float*)d_in[8];
    const float* w4 = (const float*)d_in[9];
    const float* b4 = (const float*)d_in[10];
    const float* w5 = (const float*)d_in[11];
    const float* b5 = (const float*)d_in[12];
    const float* w6 = (const float*)d_in[13];
    const float* b6 = (const float*)d_in[14];
    const float* wa = (const float*)d_in[15];
    const float* ba = (const float*)d_in[16];
    float* out = (float*)d_out;

    unsigned short* spB = (unsigned short*)d_ws;                       // 50,331,648 B
    unsigned short* waB = (unsigned short*)((char*)d_ws + 50331648);   // 294,912 B

    wa_cvt<<<dim3(36864 / 256), 256, 0, stream>>>(wa, waB);
    dw_fused<<<dim3(NBATCH * CCH), 256, 0, stream>>>(
        x, w0, b0, w1, b1, w2, b2, w3, b3, w4, b4, w5, b5, w6, b6, spB);
    pw_mfma<<<dim3(NTOT / 128, CCH / 128), 256, 0, stream>>>(spB, waB, ba, out);
}